// Round 1
// baseline (71472.388 us; speedup 1.0000x reference)
//
#include <hip/hip_runtime.h>
#include <math.h>

#define NB   256   // grid blocks (1 per CU, co-resident for grid barrier)
#define NT   512   // threads per block
#define Bsz  256
#define Ssz  256
#define Hsz  512
#define Osz  512
#define ROWS 32    // batch rows per block (8 row-groups)

// Device-scope grid barrier. All 256 blocks are co-resident (1/CU).
// Release: __syncthreads drains each wave's stores to L2, leader's
// __threadfence (agent) writes back L2; acquire: fence after spin
// invalidates stale L1/L2 lines (cross-XCD correctness).
__device__ __forceinline__ void grid_barrier(unsigned* cnt, unsigned& target) {
  __syncthreads();
  target += NB;
  if (threadIdx.x == 0) {
    __threadfence();
    __hip_atomic_fetch_add(cnt, 1u, __ATOMIC_RELAXED, __HIP_MEMORY_SCOPE_AGENT);
    while (__hip_atomic_load(cnt, __ATOMIC_RELAXED, __HIP_MEMORY_SCOPE_AGENT) < target) {
      __builtin_amdgcn_s_sleep(1);
    }
    __threadfence();
  }
  __syncthreads();
}

// Persistent GRU kernel.
// Block bid: bgrp = bid>>5 (rows b0=bgrp*32), jg = bid&31 (output col slice of 32).
// Phase A: all blocks compute g[:, jg*32 .. +32] (K=1024 over [emb(xt)|h]),
//          sigmoid -> Z (cols<512) or RH = r*h (cols>=512).
// Phase B: jg<16 -> cand cols jg*32 (K=1024 over [emb(xt)|r*h]), h_new update;
//          jg>=16 -> y_{t-1} = h_t @ Wo.T (K=512), written directly to d_out.
// Thread: j = tid>>4 (one of 32 output cols), ks = tid&15 (K-slice of 64).
// Weights live in registers for the whole kernel. shfl_xor reduces over ks.
__global__ __launch_bounds__(NT, 2) void gru_persistent(
    const int* __restrict__ x, const float* __restrict__ emb,
    const float* __restrict__ Wg, const float* __restrict__ bgp,
    const float* __restrict__ Wh, const float* __restrict__ bhp,
    const float* __restrict__ Wo, const float* __restrict__ bop,
    float* __restrict__ out, float* __restrict__ ws)
{
  const int tid  = threadIdx.x;
  const int bid  = blockIdx.x;
  const int bgrp = bid >> 5;        // 0..7
  const int jg   = bid & 31;        // 0..31
  const int b0   = bgrp * ROWS;

  const int j  = tid >> 4;          // 0..31
  const int ks = tid & 15;          // 0..15

  // workspace layout
  unsigned* cnt = (unsigned*)ws;    // barrier counter (memset to 0 on stream)
  float* H0 = ws + 64;              // h ping  [256*512] (memset to 0 = h0)
  float* H1 = H0 + Bsz * Hsz;       // h pong
  float* Z  = H1 + Bsz * Hsz;       // update gate z
  float* RH = Z  + Bsz * Hsz;       // r * h
  float* ys = out + Bsz * Hsz;      // ys output region [B,S,O]

  // ---- persistent register weights ----
  const int j0a = jg * 32;                   // phase-A gate column base (0..1023)
  float wa[64];
  {
    const float* p = Wg + (size_t)(j0a + j) * 1024 + (ks << 6);
    #pragma unroll
    for (int i = 0; i < 64; ++i) wa[i] = p[i];
  }
  const bool is_cand = (jg < 16);
  const int j0b = (jg & 15) * 32;            // cand col base or y col base (0..511)
  float wb[64];
  if (is_cand) {
    const float* p = Wh + (size_t)(j0b + j) * 1024 + (ks << 6);
    #pragma unroll
    for (int i = 0; i < 64; ++i) wb[i] = p[i];
  } else {
    const float* p = Wo + (size_t)(j0b + j) * 512 + (ks << 5);
    #pragma unroll
    for (int i = 0; i < 32; ++i) wb[i] = p[i];
    #pragma unroll
    for (int i = 32; i < 64; ++i) wb[i] = 0.0f;
  }

  __shared__ int sIdx[ROWS];
  unsigned target = 0;

  for (int t = 0; t < Ssz; ++t) {
    float* Hc = (t & 1) ? H1 : H0;
    float* Hn = (t & 1) ? H0 : H1;

    if (tid < ROWS) sIdx[tid] = x[(b0 + tid) * Ssz + t];
    __syncthreads();

    // ---------------- Phase A: gates ----------------
    for (int r = 0; r < ROWS; ++r) {
      const int b = b0 + r;
      const float* xpa = emb + (size_t)sIdx[r] * Hsz + (ks << 6);
      const float* xpb = Hc + ((size_t)b << 9) + ((ks - 8) << 6);
      const float* xp  = (ks < 8) ? xpa : xpb;
      float a0 = 0.f, a1 = 0.f, a2 = 0.f, a3 = 0.f;
      #pragma unroll
      for (int i = 0; i < 16; ++i) {
        const float4 xv = *(const float4*)(xp + i * 4);
        a0 += wa[4*i+0] * xv.x;
        a1 += wa[4*i+1] * xv.y;
        a2 += wa[4*i+2] * xv.z;
        a3 += wa[4*i+3] * xv.w;
      }
      float acc = (a0 + a1) + (a2 + a3);
      acc += __shfl_xor(acc, 1);
      acc += __shfl_xor(acc, 2);
      acc += __shfl_xor(acc, 4);
      acc += __shfl_xor(acc, 8);
      if (ks == 0) {
        const int gj = j0a + j;
        const float g = acc + bgp[gj];
        const float s = 1.0f / (1.0f + expf(-g));
        if (gj < Hsz) {
          Z[(b << 9) + gj] = s;
        } else {
          const int hj = gj - Hsz;
          RH[(b << 9) + hj] = s * Hc[(b << 9) + hj];
        }
      }
    }

    grid_barrier(cnt, target);

    // ---------------- Phase B: cand + h update | y ----------------
    if (is_cand) {
      for (int r = 0; r < ROWS; ++r) {
        const int b = b0 + r;
        const float* xpa = emb + (size_t)sIdx[r] * Hsz + (ks << 6);
        const float* xpb = RH + ((size_t)b << 9) + ((ks - 8) << 6);
        const float* xp  = (ks < 8) ? xpa : xpb;
        float a0 = 0.f, a1 = 0.f, a2 = 0.f, a3 = 0.f;
        #pragma unroll
        for (int i = 0; i < 16; ++i) {
          const float4 xv = *(const float4*)(xp + i * 4);
          a0 += wb[4*i+0] * xv.x;
          a1 += wb[4*i+1] * xv.y;
          a2 += wb[4*i+2] * xv.z;
          a3 += wb[4*i+3] * xv.w;
        }
        float acc = (a0 + a1) + (a2 + a3);
        acc += __shfl_xor(acc, 1);
        acc += __shfl_xor(acc, 2);
        acc += __shfl_xor(acc, 4);
        acc += __shfl_xor(acc, 8);
        if (ks == 0) {
          const int jc = j0b + j;
          const float cand = tanhf(acc + bhp[jc]);
          const float zv = Z[(b << 9) + jc];
          const float hv = Hc[(b << 9) + jc];
          Hn[(b << 9) + jc] = (1.0f - zv) * hv + zv * cand;
        }
      }
    } else if (t > 0) {
      for (int r = 0; r < ROWS; ++r) {
        const int b = b0 + r;
        const float* xp = Hc + ((size_t)b << 9) + (ks << 5);
        float a0 = 0.f, a1 = 0.f, a2 = 0.f, a3 = 0.f;
        #pragma unroll
        for (int i = 0; i < 8; ++i) {
          const float4 xv = *(const float4*)(xp + i * 4);
          a0 += wb[4*i+0] * xv.x;
          a1 += wb[4*i+1] * xv.y;
          a2 += wb[4*i+2] * xv.z;
          a3 += wb[4*i+3] * xv.w;
        }
        float acc = (a0 + a1) + (a2 + a3);
        acc += __shfl_xor(acc, 1);
        acc += __shfl_xor(acc, 2);
        acc += __shfl_xor(acc, 4);
        acc += __shfl_xor(acc, 8);
        if (ks == 0) {
          const int jo = j0b + j;
          ys[((size_t)b * Ssz + (t - 1)) * Osz + jo] = acc + bop[jo];
        }
      }
    }

    grid_barrier(cnt, target);
  }

  // ---- tail: h_final copy + y_{S-1} from h_S (h_S lives in H0: S even) ----
  float* Hf = H0;
  if (is_cand) {
    for (int i = tid; i < ROWS * 32; i += NT) {
      const int r = i >> 5, c = i & 31;
      out[((b0 + r) << 9) + j0b + c] = Hf[((b0 + r) << 9) + j0b + c];
    }
  } else {
    for (int r = 0; r < ROWS; ++r) {
      const int b = b0 + r;
      const float* xp = Hf + ((size_t)b << 9) + (ks << 5);
      float a0 = 0.f, a1 = 0.f, a2 = 0.f, a3 = 0.f;
      #pragma unroll
      for (int i = 0; i < 8; ++i) {
        const float4 xv = *(const float4*)(xp + i * 4);
        a0 += wb[4*i+0] * xv.x;
        a1 += wb[4*i+1] * xv.y;
        a2 += wb[4*i+2] * xv.z;
        a3 += wb[4*i+3] * xv.w;
      }
      float acc = (a0 + a1) + (a2 + a3);
      acc += __shfl_xor(acc, 1);
      acc += __shfl_xor(acc, 2);
      acc += __shfl_xor(acc, 4);
      acc += __shfl_xor(acc, 8);
      if (ks == 0) {
        const int jo = j0b + j;
        ys[((size_t)b * Ssz + (Ssz - 1)) * Osz + jo] = acc + bop[jo];
      }
    }
  }
}

extern "C" void kernel_launch(void* const* d_in, const int* in_sizes, int n_in,
                              void* d_out, int out_size, void* d_ws, size_t ws_size,
                              hipStream_t stream) {
  const int*   x   = (const int*)  d_in[0];
  const float* emb = (const float*)d_in[1];
  const float* Wg  = (const float*)d_in[2];
  const float* bg  = (const float*)d_in[3];
  const float* Wh  = (const float*)d_in[4];
  const float* bh  = (const float*)d_in[5];
  const float* Wo  = (const float*)d_in[6];
  const float* bo  = (const float*)d_in[7];
  float* out = (float*)d_out;
  float* ws  = (float*)d_ws;

  // Zero the barrier counter (256 B header) and H0 (= h0 zeros, 512 KB).
  // ws re-poisoned to 0xAA before every launch, so this must run every call.
  hipMemsetAsync(d_ws, 0, 256 + Bsz * Hsz * sizeof(float), stream);

  gru_persistent<<<NB, NT, 0, stream>>>(x, emb, Wg, bg, Wh, bh, Wo, bo, out, ws);
}

// Round 2
// 16311.372 us; speedup vs baseline: 4.3818x; 4.3818x over previous
//
#include <hip/hip_runtime.h>
#include <math.h>

#define NB   256   // one block per CU — co-resident for the grid barrier
#define NT   512
#define Bsz  256
#define Ssz  256
#define Hsz  512
#define Osz  512

#define AGENT __HIP_MEMORY_SCOPE_AGENT
#define RLX   __ATOMIC_RELAXED

// Dynamic LDS: 32 rows x 1024 floats (128 KB). Layout per row is a
// float4-granular transpose: element k (0..1023) of the x-vector
// [emb(x_t) | h] lives at  T(k) = ((k>>2)&15)*64 + (k>>6)*4 + (k&3).
// GEMM reader thread ks then reads 16 ds_read_b128 at base ks*4 with
// compile-time offsets i*64 floats; lanes ks=0..15 start at banks 4*ks
// (2-way aliasing only = free per m136).
extern __shared__ float sx[];

// Fence-free grid barrier. Release: __syncthreads() drains every wave's
// vmcnt (all agent-scope atomic stores have reached the LLC coherence
// point). No __threadfence -> no L2 writeback/invalidate (round-1's 20x
// slowdown). All cross-block data moves via agent-scope relaxed atomics
// which bypass L1/L2, so plain caches never hold stale shared data.
__device__ __forceinline__ void grid_barrier(unsigned* cnt, unsigned& target) {
  __syncthreads();
  target += NB;
  if (threadIdx.x == 0) {
    __hip_atomic_fetch_add(cnt, 1u, RLX, AGENT);
    while (__hip_atomic_load(cnt, RLX, AGENT) < target)
      __builtin_amdgcn_s_sleep(1);
  }
  __syncthreads();
}

__device__ __forceinline__ int ldsT_h(int r, int c) {
  // LDS float-index of h-element c (global k = 512 + c) in row r
  return (r << 10) + (((c >> 2) & 15) << 6) + 32 + ((c >> 6) << 2) + (c & 3);
}

__global__ __launch_bounds__(NT, 2) void gru_persistent(
    const int* __restrict__ x, const float* __restrict__ emb,
    const float* __restrict__ Wg, const float* __restrict__ bgp,
    const float* __restrict__ Wh, const float* __restrict__ bhp,
    const float* __restrict__ Wo, const float* __restrict__ bop,
    float* __restrict__ out, float* __restrict__ ws)
{
  const int tid  = threadIdx.x;
  const int bid  = blockIdx.x;
  const int bgrp = bid >> 5;          // 8 row-groups of 32 batch rows
  const int jg   = bid & 31;          // 32 column-slice groups
  const int b0   = bgrp << 5;
  const int j    = tid >> 4;          // output col within slice (0..31)
  const int ks   = tid & 15;          // K-slice (64 floats each)
  const bool is_cand = (jg < 16);     // z-gate + cand blocks vs r-gate + y blocks
  const int j0a = jg << 5;            // phase-A gate col base (0..1023)
  const int j0b = (jg & 15) << 5;     // phase-B col base (0..511)

  unsigned* cnt = (unsigned*)ws;
  float* H0 = ws + 64;                // [256][512] h ping (memset 0 = h0)
  float* H1 = H0 + Bsz * Hsz;         // h pong
  float* RH = H1 + Bsz * Hsz;         // r*h, produced phase A, consumed phase B
  float* ys = out + Bsz * Hsz;

  __shared__ float szv[32][32];       // z values (block-local reuse A->B)
  __shared__ float shv[32][32];       // h_old at this block's cand cols
  __shared__ int   sIdx[32];

  // ---- persistent register weights (constant-indexed -> VGPR resident) ----
  float4 wa4[16];
  {
    const float4* p = (const float4*)(Wg + (size_t)(j0a + j) * 1024 + (ks << 6));
    #pragma unroll
    for (int i = 0; i < 16; ++i) wa4[i] = p[i];
  }
  float4 wb4[16];
  if (is_cand) {
    const float4* p = (const float4*)(Wh + (size_t)(j0b + j) * 1024 + (ks << 6));
    #pragma unroll
    for (int i = 0; i < 16; ++i) wb4[i] = p[i];
  } else {
    const float4* p = (const float4*)(Wo + (size_t)(j0b + j) * 512 + (ks << 5));
    #pragma unroll
    for (int i = 0; i < 8; ++i) wb4[i] = p[i];
    #pragma unroll
    for (int i = 8; i < 16; ++i) wb4[i] = make_float4(0.f, 0.f, 0.f, 0.f);
  }
  const float bA = bgp[j0a + j];
  const float bB = is_cand ? bhp[j0b + j] : bop[j0b + j];

  unsigned target = 0;

  for (int t = 0; t < Ssz; ++t) {
    float* Hc = (t & 1) ? H1 : H0;
    float* Hn = (t & 1) ? H0 : H1;

    if (tid < 32) sIdx[tid] = x[(b0 + tid) * Ssz + t];
    __syncthreads();

    // ---- stage emb half (normal cached loads; read-only data) ----
    {
      const int r = tid >> 4, l = tid & 15;
      const float4* ep = (const float4*)(emb + (size_t)sIdx[r] * Hsz);
      #pragma unroll
      for (int kk = 0; kk < 8; ++kk) {
        float4 v = ep[(kk << 4) + l];
        *(float4*)&sx[(r << 10) + (l << 6) + (kk << 2)] = v;
      }
    }
    // ---- stage h half: Hc rows via LLC (agent atomics, 8B) ----
    #pragma unroll
    for (int kk = 0; kk < 16; ++kk) {
      const int pi = (kk << 9) + tid;           // pair index
      const int r  = pi >> 8;
      const int kh = (pi & 255) << 1;
      unsigned long long v = __hip_atomic_load(
          (const unsigned long long*)(Hc + (((size_t)(b0 + r)) << 9) + kh), RLX, AGENT);
      *(unsigned long long*)&sx[ldsT_h(r, kh)] = v;
    }
    __syncthreads();

    // ---------------- Phase A: gates ----------------
    #pragma unroll 2
    for (int r = 0; r < 32; ++r) {
      const float* xp = &sx[(r << 10) + (ks << 2)];
      float a0 = 0.f, a1 = 0.f, a2 = 0.f, a3 = 0.f;
      #pragma unroll
      for (int i = 0; i < 16; ++i) {
        const float4 xv = *(const float4*)(xp + (i << 6));
        a0 += wa4[i].x * xv.x; a1 += wa4[i].y * xv.y;
        a2 += wa4[i].z * xv.z; a3 += wa4[i].w * xv.w;
      }
      float acc = (a0 + a1) + (a2 + a3);
      acc += __shfl_xor(acc, 1);
      acc += __shfl_xor(acc, 2);
      acc += __shfl_xor(acc, 4);
      acc += __shfl_xor(acc, 8);
      if (ks == 0) {
        const float s = 1.f / (1.f + expf(-(acc + bA)));
        if (is_cand) {
          szv[r][j] = s;
          shv[r][j] = sx[ldsT_h(r, j0b + j)];
        } else {
          const int hj = j0a + j - 512;
          const float hv = sx[ldsT_h(r, hj)];
          __hip_atomic_store(RH + (((size_t)(b0 + r)) << 9) + hj, s * hv, RLX, AGENT);
        }
      }
    }

    grid_barrier(cnt, target);

    // ---------------- Phase B ----------------
    if (is_cand) {
      // restage h-half with r*h (from LLC)
      #pragma unroll
      for (int kk = 0; kk < 16; ++kk) {
        const int pi = (kk << 9) + tid;
        const int r  = pi >> 8;
        const int kh = (pi & 255) << 1;
        unsigned long long v = __hip_atomic_load(
            (const unsigned long long*)(RH + (((size_t)(b0 + r)) << 9) + kh), RLX, AGENT);
        *(unsigned long long*)&sx[ldsT_h(r, kh)] = v;
      }
      __syncthreads();
      #pragma unroll 2
      for (int r = 0; r < 32; ++r) {
        const float* xp = &sx[(r << 10) + (ks << 2)];
        float a0 = 0.f, a1 = 0.f, a2 = 0.f, a3 = 0.f;
        #pragma unroll
        for (int i = 0; i < 16; ++i) {
          const float4 xv = *(const float4*)(xp + (i << 6));
          a0 += wb4[i].x * xv.x; a1 += wb4[i].y * xv.y;
          a2 += wb4[i].z * xv.z; a3 += wb4[i].w * xv.w;
        }
        float acc = (a0 + a1) + (a2 + a3);
        acc += __shfl_xor(acc, 1);
        acc += __shfl_xor(acc, 2);
        acc += __shfl_xor(acc, 4);
        acc += __shfl_xor(acc, 8);
        if (ks == 0) {
          const float cd = tanhf(acc + bB);
          const float zv = szv[r][j], hv = shv[r][j];
          const float hn = (1.f - zv) * hv + zv * cd;
          __hip_atomic_store(Hn + (((size_t)(b0 + r)) << 9) + (j0b + j), hn, RLX, AGENT);
          if (t == Ssz - 1) out[((b0 + r) << 9) + (j0b + j)] = hn;
        }
      }
    } else if (t > 0) {
      const int ybase = ((ks & 1) << 9) + 32 + ((ks >> 1) << 2);
      #pragma unroll 2
      for (int r = 0; r < 32; ++r) {
        const float* xp = &sx[(r << 10) + ybase];
        float a0 = 0.f, a1 = 0.f, a2 = 0.f, a3 = 0.f;
        #pragma unroll
        for (int i = 0; i < 8; ++i) {
          const float4 xv = *(const float4*)(xp + (i << 6));
          a0 += wb4[i].x * xv.x; a1 += wb4[i].y * xv.y;
          a2 += wb4[i].z * xv.z; a3 += wb4[i].w * xv.w;
        }
        float acc = (a0 + a1) + (a2 + a3);
        acc += __shfl_xor(acc, 1);
        acc += __shfl_xor(acc, 2);
        acc += __shfl_xor(acc, 4);
        acc += __shfl_xor(acc, 8);
        if (ks == 0)
          ys[((size_t)(b0 + r) * Ssz + (t - 1)) * Osz + (j0b + j)] = acc + bB;
      }
    }

    grid_barrier(cnt, target);
  }

  // ---- tail: y_{S-1} from h_S (Ssz even -> h_S in H0) ----
  if (!is_cand) {
    #pragma unroll
    for (int kk = 0; kk < 16; ++kk) {
      const int pi = (kk << 9) + tid;
      const int r  = pi >> 8;
      const int kh = (pi & 255) << 1;
      unsigned long long v = __hip_atomic_load(
          (const unsigned long long*)(H0 + (((size_t)(b0 + r)) << 9) + kh), RLX, AGENT);
      *(unsigned long long*)&sx[ldsT_h(r, kh)] = v;
    }
    __syncthreads();
    const int ybase = ((ks & 1) << 9) + 32 + ((ks >> 1) << 2);
    #pragma unroll 2
    for (int r = 0; r < 32; ++r) {
      const float* xp = &sx[(r << 10) + ybase];
      float a0 = 0.f, a1 = 0.f, a2 = 0.f, a3 = 0.f;
      #pragma unroll
      for (int i = 0; i < 8; ++i) {
        const float4 xv = *(const float4*)(xp + (i << 6));
        a0 += wb4[i].x * xv.x; a1 += wb4[i].y * xv.y;
        a2 += wb4[i].z * xv.z; a3 += wb4[i].w * xv.w;
      }
      float acc = (a0 + a1) + (a2 + a3);
      acc += __shfl_xor(acc, 1);
      acc += __shfl_xor(acc, 2);
      acc += __shfl_xor(acc, 4);
      acc += __shfl_xor(acc, 8);
      if (ks == 0)
        ys[((size_t)(b0 + r) * Ssz + (Ssz - 1)) * Osz + (j0b + j)] = acc + bB;
    }
  }
}

extern "C" void kernel_launch(void* const* d_in, const int* in_sizes, int n_in,
                              void* d_out, int out_size, void* d_ws, size_t ws_size,
                              hipStream_t stream) {
  const int*   x   = (const int*)  d_in[0];
  const float* emb = (const float*)d_in[1];
  const float* Wg  = (const float*)d_in[2];
  const float* bg  = (const float*)d_in[3];
  const float* Wh  = (const float*)d_in[4];
  const float* bh  = (const float*)d_in[5];
  const float* Wo  = (const float*)d_in[6];
  const float* bo  = (const float*)d_in[7];
  float* out = (float*)d_out;
  float* ws  = (float*)d_ws;

  // 128 KB dynamic LDS opt-in (host-side attribute, graph-capture safe)
  hipFuncSetAttribute((const void*)gru_persistent,
                      hipFuncAttributeMaxDynamicSharedMemorySize, 32 * 1024 * 4);

  // Zero barrier counter + H0 (= h0). ws is re-poisoned before every launch.
  hipMemsetAsync(d_ws, 0, (64 + Bsz * Hsz) * sizeof(float), stream);

  gru_persistent<<<NB, NT, 32 * 1024 * 4, stream>>>(x, emb, Wg, bg, Wh, bh, Wo, bo, out, ws);
}

// Round 3
// 15523.529 us; speedup vs baseline: 4.6041x; 1.0508x over previous
//
#include <hip/hip_runtime.h>
#include <math.h>

#define NB   256   // one block per CU — co-resident (132 KB LDS forces 1/CU)
#define NT   512
#define Bsz  256
#define Ssz  256
#define Hsz  512
#define Osz  512
#define RSTRIDE 1032   // LDS row stride in floats (1024 + 8 pad: spreads bank quads)

#define AGENT __HIP_MEMORY_SCOPE_AGENT
#define RLX   __ATOMIC_RELAXED

// Dynamic LDS: 32 rows x RSTRIDE floats (132 KB). Within a row, the 1024-float
// x-vector [emb(x_t) | h] is stored slot-transposed at float4 granularity:
// group g = k>>2 lives at slot (g&15)*16 + (g>>4), i.e. float-idx
// (slot<<2)|(k&3). GEMM reader thread ks then reads 16B at base ks*4 with
// compile-time offsets i*256B; the 16 ks-lanes cover one contiguous 256B run
// (2 bank rows, 2-way = free). emb occupies slot%16 in 0..7, h in 8..15.
extern __shared__ float sx[];

__device__ __forceinline__ int ldsT_h(int r, int c) {
  // float-idx of h element c (global k = 512+c) in row r
  return r * RSTRIDE + (((c >> 2) & 15) << 6) + 32 + ((c >> 6) << 2) + (c & 3);
}

// Contention-free grid barrier: per-block flags (no RMW), parallel poll.
// Release: every wave drains its outstanding stores (s_waitcnt 0) BEFORE
// __syncthreads, so all agent-scope stores are LLC-visible before the flag
// store. No __threadfence => no L2 writeback/invalidate storms.
__device__ __forceinline__ void grid_barrier(unsigned* flags, unsigned& target) {
  ++target;
  __builtin_amdgcn_s_waitcnt(0);      // drain this wave's vm/lgkm (release)
  __syncthreads();
  __atomic_signal_fence(__ATOMIC_SEQ_CST);
  if (threadIdx.x == 0)
    __hip_atomic_store(&flags[blockIdx.x], target, RLX, AGENT);
  if (threadIdx.x < NB) {
    while (__hip_atomic_load(&flags[threadIdx.x], RLX, AGENT) < target)
      __builtin_amdgcn_s_sleep(2);
  }
  __atomic_signal_fence(__ATOMIC_SEQ_CST);
  __syncthreads();
}

// Stage the h-half of all 32 rows from global buffer src (agent-scope loads
// bypass L1/L2 -> no stale data). Lane-rotated kk spreads LDS bank quads.
__device__ __forceinline__ void stage_h(const float* src, int b0, int tid) {
  const int r = tid >> 4, l = tid & 15;
  const float* rowp = src + (((size_t)(b0 + r)) << 9);
  #pragma unroll
  for (int m = 0; m < 8; ++m) {
    const int kk = (m + l) & 7;
    const int c0 = (kk << 6) + (l << 2);          // float4-aligned c
    unsigned long long v0 = __hip_atomic_load(
        (const unsigned long long*)(rowp + c0), RLX, AGENT);
    unsigned long long v1 = __hip_atomic_load(
        (const unsigned long long*)(rowp + c0 + 2), RLX, AGENT);
    float* d = &sx[r * RSTRIDE + (l << 6) + 32 + (kk << 2)];
    *(unsigned long long*)d       = v0;
    *(unsigned long long*)(d + 2) = v1;
  }
}

__global__ __launch_bounds__(NT, 2) void gru_persistent(
    const int* __restrict__ x, const float* __restrict__ emb,
    const float* __restrict__ Wg, const float* __restrict__ bgp,
    const float* __restrict__ Wh, const float* __restrict__ bhp,
    const float* __restrict__ Wo, const float* __restrict__ bop,
    float* __restrict__ out, float* __restrict__ ws)
{
  const int tid  = threadIdx.x;
  const int bid  = blockIdx.x;
  const int bgrp = bid >> 5;          // 8 row-groups of 32 batch rows
  const int jg   = bid & 31;          // 32 column-slice groups
  const int b0   = bgrp << 5;
  const int j    = tid >> 4;          // output col within slice (0..31)
  const int ks   = tid & 15;          // K-slice (64 floats)
  const bool is_cand = (jg < 16);
  const int j0a = jg << 5;            // phase-A gate col base (0..1023)
  const int j0b = (jg & 15) << 5;     // phase-B col base (0..511)

  unsigned* flags = (unsigned*)ws;    // [256] barrier flags (memset 0)
  float* H0 = ws + 256;               // [256][512] h ping (memset 0 = h0)
  float* H1 = H0 + Bsz * Hsz;
  float* RH = H1 + Bsz * Hsz;
  float* ys = out + Bsz * Hsz;

  __shared__ float szv[32][32];
  __shared__ float shv[32][32];
  __shared__ int   sIdx[32];

  // ---- persistent register weights ----
  float4 wa4[16];
  {
    const float4* p = (const float4*)(Wg + (size_t)(j0a + j) * 1024 + (ks << 6));
    #pragma unroll
    for (int i = 0; i < 16; ++i) wa4[i] = p[i];
  }
  float4 wb4[16];
  if (is_cand) {
    const float4* p = (const float4*)(Wh + (size_t)(j0b + j) * 1024 + (ks << 6));
    #pragma unroll
    for (int i = 0; i < 16; ++i) wb4[i] = p[i];
  } else {
    const float4* p = (const float4*)(Wo + (size_t)(j0b + j) * 512 + (ks << 5));
    #pragma unroll
    for (int i = 0; i < 8; ++i) wb4[i] = p[i];
    #pragma unroll
    for (int i = 8; i < 16; ++i) wb4[i] = make_float4(0.f, 0.f, 0.f, 0.f);
  }
  const float bA = bgp[j0a + j];
  const float bB = is_cand ? bhp[j0b + j] : bop[j0b + j];

  unsigned target = 0;

  for (int t = 0; t < Ssz; ++t) {
    float* Hc = (t & 1) ? H1 : H0;
    float* Hn = (t & 1) ? H0 : H1;

    if (tid < 32) sIdx[tid] = x[(b0 + tid) * Ssz + t];
    __syncthreads();

    // ---- stage emb half (plain cached loads; read-only) ----
    {
      const int r = tid >> 4, l = tid & 15;
      const float4* ep = (const float4*)(emb + (size_t)sIdx[r] * Hsz);
      #pragma unroll
      for (int m = 0; m < 8; ++m) {
        const int kk = (m + l) & 7;                 // lane-rotated: bank spread
        float4 v = ep[(kk << 4) + l];
        *(float4*)&sx[r * RSTRIDE + (l << 6) + (kk << 2)] = v;
      }
    }
    // ---- stage h half via LLC ----
    stage_h(Hc, b0, tid);
    __syncthreads();

    // ---------------- Phase A: gates ----------------
    {
      const int bx = (ks << 2);
      #pragma unroll 2
      for (int r = 0; r < 32; ++r) {
        const float* xp = &sx[r * RSTRIDE + bx];
        float a0 = 0.f, a1 = 0.f, a2 = 0.f, a3 = 0.f;
        #pragma unroll
        for (int i = 0; i < 16; ++i) {
          const float4 xv = *(const float4*)(xp + (i << 6));
          a0 += wa4[i].x * xv.x; a1 += wa4[i].y * xv.y;
          a2 += wa4[i].z * xv.z; a3 += wa4[i].w * xv.w;
        }
        float acc = (a0 + a1) + (a2 + a3);
        acc += __shfl_xor(acc, 1);
        acc += __shfl_xor(acc, 2);
        acc += __shfl_xor(acc, 4);
        acc += __shfl_xor(acc, 8);
        if (ks == 0) {
          const float s = 1.f / (1.f + expf(-(acc + bA)));
          if (is_cand) {
            szv[r][j] = s;
            shv[r][j] = sx[ldsT_h(r, j0b + j)];
          } else {
            const int hj = j0a + j - 512;
            const float hv = sx[ldsT_h(r, hj)];
            __hip_atomic_store(RH + (((size_t)(b0 + r)) << 9) + hj, s * hv, RLX, AGENT);
          }
        }
      }
    }

    grid_barrier(flags, target);

    // ---------------- Phase B ----------------
    if (is_cand) {
      stage_h(RH, b0, tid);     // overwrite h-half with r*h
      __syncthreads();
      const int bx = (ks << 2);
      #pragma unroll 2
      for (int r = 0; r < 32; ++r) {
        const float* xp = &sx[r * RSTRIDE + bx];
        float a0 = 0.f, a1 = 0.f, a2 = 0.f, a3 = 0.f;
        #pragma unroll
        for (int i = 0; i < 16; ++i) {
          const float4 xv = *(const float4*)(xp + (i << 6));
          a0 += wb4[i].x * xv.x; a1 += wb4[i].y * xv.y;
          a2 += wb4[i].z * xv.z; a3 += wb4[i].w * xv.w;
        }
        float acc = (a0 + a1) + (a2 + a3);
        acc += __shfl_xor(acc, 1);
        acc += __shfl_xor(acc, 2);
        acc += __shfl_xor(acc, 4);
        acc += __shfl_xor(acc, 8);
        if (ks == 0) {
          const float cd = tanhf(acc + bB);
          const float zv = szv[r][j], hv = shv[r][j];
          const float hn = (1.f - zv) * hv + zv * cd;
          __hip_atomic_store(Hn + (((size_t)(b0 + r)) << 9) + (j0b + j), hn, RLX, AGENT);
          if (t == Ssz - 1) out[((b0 + r) << 9) + (j0b + j)] = hn;
        }
      }
    } else if (t > 0) {
      const int by = ((ks & 1) << 9) + 32 + ((ks >> 1) << 2);
      #pragma unroll 2
      for (int r = 0; r < 32; ++r) {
        const float* xp = &sx[r * RSTRIDE + by];
        float a0 = 0.f, a1 = 0.f, a2 = 0.f, a3 = 0.f;
        #pragma unroll
        for (int i = 0; i < 8; ++i) {
          const float4 xv = *(const float4*)(xp + (i << 6));
          a0 += wb4[i].x * xv.x; a1 += wb4[i].y * xv.y;
          a2 += wb4[i].z * xv.z; a3 += wb4[i].w * xv.w;
        }
        float acc = (a0 + a1) + (a2 + a3);
        acc += __shfl_xor(acc, 1);
        acc += __shfl_xor(acc, 2);
        acc += __shfl_xor(acc, 4);
        acc += __shfl_xor(acc, 8);
        if (ks == 0)
          ys[((size_t)(b0 + r) * Ssz + (t - 1)) * Osz + (j0b + j)] = acc + bB;
      }
    }

    grid_barrier(flags, target);
  }

  // ---- tail: y_{S-1} from h_S (Ssz even -> h_S in H0) ----
  if (!is_cand) {
    stage_h(H0, b0, tid);
    __syncthreads();
    const int by = ((ks & 1) << 9) + 32 + ((ks >> 1) << 2);
    #pragma unroll 2
    for (int r = 0; r < 32; ++r) {
      const float* xp = &sx[r * RSTRIDE + by];
      float a0 = 0.f, a1 = 0.f, a2 = 0.f, a3 = 0.f;
      #pragma unroll
      for (int i = 0; i < 8; ++i) {
        const float4 xv = *(const float4*)(xp + (i << 6));
        a0 += wb4[i].x * xv.x; a1 += wb4[i].y * xv.y;
        a2 += wb4[i].z * xv.z; a3 += wb4[i].w * xv.w;
      }
      float acc = (a0 + a1) + (a2 + a3);
      acc += __shfl_xor(acc, 1);
      acc += __shfl_xor(acc, 2);
      acc += __shfl_xor(acc, 4);
      acc += __shfl_xor(acc, 8);
      if (ks == 0)
        ys[((size_t)(b0 + r) * Ssz + (Ssz - 1)) * Osz + (j0b + j)] = acc + bB;
    }
  }
}

extern "C" void kernel_launch(void* const* d_in, const int* in_sizes, int n_in,
                              void* d_out, int out_size, void* d_ws, size_t ws_size,
                              hipStream_t stream) {
  const int*   x   = (const int*)  d_in[0];
  const float* emb = (const float*)d_in[1];
  const float* Wg  = (const float*)d_in[2];
  const float* bg  = (const float*)d_in[3];
  const float* Wh  = (const float*)d_in[4];
  const float* bh  = (const float*)d_in[5];
  const float* Wo  = (const float*)d_in[6];
  const float* bo  = (const float*)d_in[7];
  float* out = (float*)d_out;
  float* ws  = (float*)d_ws;

  const int dynLds = 32 * RSTRIDE * 4;   // 132,096 B
  hipFuncSetAttribute((const void*)gru_persistent,
                      hipFuncAttributeMaxDynamicSharedMemorySize, dynLds);

  // Zero barrier flags (256 u32) + H0 (= h0). ws re-poisoned every launch.
  hipMemsetAsync(d_ws, 0, (256 + Bsz * Hsz) * sizeof(float), stream);

  gru_persistent<<<NB, NT, dynLds, stream>>>(x, emb, Wg, bg, Wh, bh, Wo, bo, out, ws);
}